// Round 10
// baseline (1130.389 us; speedup 1.0000x reference)
//
#include <hip/hip_runtime.h>
#include <math.h>

#define NBLK 64

typedef __attribute__((ext_vector_type(8))) short short8;
typedef __attribute__((ext_vector_type(8))) _Float16 f16x8;
typedef __attribute__((ext_vector_type(4))) float f32x4;

__device__ __forceinline__ void split_f16(float f, unsigned short& h, unsigned short& l){
  _Float16 hh = (_Float16)f;
  _Float16 ll = (_Float16)(f - (float)hh);
  h = __builtin_bit_cast(unsigned short, hh);
  l = __builtin_bit_cast(unsigned short, ll);
}

__device__ __forceinline__ float fsig(float xv){ return 1.f / (1.f + __expf(-xv)); }
__device__ __forceinline__ float ftanh(float xv){ return 1.f - 2.f / (1.f + __expf(2.f * xv)); }

__global__ __launch_bounds__(256, 1) void lstm_persist(
    const float* __restrict__ x,
    const float* __restrict__ hidden0,
    const float* __restrict__ W_hid,
    const float* __restrict__ b_hid,
    const float* __restrict__ W_ih,
    const float* __restrict__ W_hh,
    const float* __restrict__ b_ih,
    const float* __restrict__ b_hh,
    float* __restrict__ out,
    float* __restrict__ out_h0,
    unsigned* __restrict__ flags,     // [64] one-time x-init barrier
    unsigned* __restrict__ hsteps,    // [256][32][512] packed (f16hi<<16|f16lo); 0xFFFFFFFF = not ready
    unsigned short* __restrict__ xhi, // [32][256][64] f16 bits
    unsigned short* __restrict__ xlo)
{
  __shared__ unsigned short hs_hi[2][16384];  // 2 x 32KB hi-plane only, XOR-swizzled

  const int tid  = threadIdx.x;
  const int bid  = blockIdx.x;
  const int lane = tid & 63;
  const int wid  = tid >> 6;   // 0..3
  const int cc   = wid & 1;    // batch half
  const int jh   = wid >> 1;   // j-half (4 cols each)
  const int m    = lane & 15;
  const int g    = lane >> 4;
  const int J0   = bid * 8;
  const int gid  = bid * 256 + tid;

  const int b_own = cc * 16 + m;        // C col (batch); also B-frag batch row
  const int j_own = J0 + jh * 4 + g;    // C rows g*4+q = gates q of this j
  const int RW = (m & 3) * 512 + J0 + jh * 4 + (m >> 2);   // A-row rr=jj*4+gate -> W row

  // ---------------- init: h0 = hidden0 @ W_hid^T + b_hid ----------------
  {
    int b = gid >> 9, hc = gid & 511;
    const float* hv = hidden0 + b * 64;
    const float* wv = W_hid + hc * 64;
    float acc = b_hid[hc];
    #pragma unroll
    for (int d = 0; d < 64; d += 4){
      float4 a = *(const float4*)(hv + d);
      float4 w = *(const float4*)(wv + d);
      acc += a.x*w.x + a.y*w.y + a.z*w.z + a.w*w.w;
    }
    out_h0[gid] = acc;                       // second output
    unsigned short hh, ll; split_f16(acc, hh, ll);
    unsigned packed = ((unsigned)hh << 16) | (unsigned)ll;  // finite => hi16 != 0xFFFF
    asm volatile("global_store_dword %0, %1, off sc0 sc1" :: "v"(hsteps + gid), "v"(packed) : "memory");
  }
  // ---------------- init: x -> f16 hi/lo (write-through) ----------------
  {
    const float4* x4 = (const float4*)x;
    #pragma unroll
    for (int k = 0; k < 8; ++k){
      int v = gid + k * 16384;
      float4 f = x4[v];
      unsigned short ha,la,hb2,lb2,hc2,lc2,hd,ld;
      split_f16(f.x,ha,la); split_f16(f.y,hb2,lb2);
      split_f16(f.z,hc2,lc2); split_f16(f.w,hd,ld);
      uint2 ph, pl;
      ph.x = (unsigned)ha | ((unsigned)hb2 << 16);
      ph.y = (unsigned)hc2 | ((unsigned)hd << 16);
      pl.x = (unsigned)la | ((unsigned)lb2 << 16);
      pl.y = (unsigned)lc2 | ((unsigned)ld << 16);
      asm volatile("global_store_dwordx2 %0, %1, off sc0 sc1" :: "v"(xhi + (size_t)v*4), "v"(ph) : "memory");
      asm volatile("global_store_dwordx2 %0, %1, off sc0 sc1" :: "v"(xlo + (size_t)v*4), "v"(pl) : "memory");
    }
  }
  // ---------------- own c0, exact f32 ----------------
  float c_state;
  {
    const float* hv = hidden0 + b_own * 64;
    const float* wv = W_hid + j_own * 64;
    float acc = b_hid[j_own];
    #pragma unroll
    for (int d = 0; d < 64; d += 4){
      float4 a = *(const float4*)(hv + d);
      float4 w = *(const float4*)(wv + d);
      acc += a.x*w.x + a.y*w.y + a.z*w.z + a.w*w.w;
    }
    c_state = acc;
  }

  // ---------------- W_hh fragments -> registers (once) ----------------
  f16x8 whh_hi[16], whh_lo[16];
  #pragma unroll
  for (int kc = 0; kc < 16; ++kc){
    const float* p = W_hh + RW * 512 + kc * 32 + g * 8;
    float4 f0 = *(const float4*)p;
    float4 f1 = *(const float4*)(p + 4);
    float fs[8] = {f0.x,f0.y,f0.z,f0.w,f1.x,f1.y,f1.z,f1.w};
    short8 hb8, lb8;
    #pragma unroll
    for (int i = 0; i < 8; ++i){
      unsigned short hh, ll; split_f16(fs[i], hh, ll);
      hb8[i] = (short)hh; lb8[i] = (short)ll;
    }
    whh_hi[kc] = __builtin_bit_cast(f16x8, hb8);
    whh_lo[kc] = __builtin_bit_cast(f16x8, lb8);
  }

  const float bias_i = b_ih[j_own]        + b_hh[j_own];
  const float bias_f = b_ih[512 + j_own]  + b_hh[512 + j_own];
  const float bias_g = b_ih[1024 + j_own] + b_hh[1024 + j_own];
  const float bias_o = b_ih[1536 + j_own] + b_hh[1536 + j_own];

  // ---------------- one-time barrier: x f16 conversion complete ----------------
  asm volatile("s_waitcnt vmcnt(0)" ::: "memory");
  __syncthreads();
  if (tid == 0){
    unsigned one = 1;
    asm volatile("global_store_dword %0, %1, off sc0 sc1" :: "v"(flags + bid), "v"(one) : "memory");
  }
  {
    const unsigned* fp = flags + lane;
    while (true){
      unsigned fv;
      asm volatile("global_load_dword %0, %1, off sc0 sc1\n\ts_waitcnt vmcnt(0)"
                   : "=v"(fv) : "v"(fp) : "memory");
      if (__all((int)(fv >= 1u))) break;
      __builtin_amdgcn_s_sleep(1);
    }
  }

  // persistent x@W_ih prefix-sum accumulators (x-side keeps full 3-term split)
  f32x4 axc0 = {0.f,0.f,0.f,0.f}, axc1 = axc0, axc2 = axc0;

  auto cvt8 = [](float4 f0, float4 f1, f16x8& hi, f16x8& lo){
    float fs[8] = {f0.x,f0.y,f0.z,f0.w,f1.x,f1.y,f1.z,f1.w};
    short8 hb8, lb8;
    #pragma unroll
    for (int i = 0; i < 8; ++i){
      unsigned short hh, ll; split_f16(fs[i], hh, ll);
      hb8[i] = (short)hh; lb8[i] = (short)ll;
    }
    hi = __builtin_bit_cast(f16x8, hb8);
    lo = __builtin_bit_cast(f16x8, lb8);
  };

  // step-0 x-part (cold, serial once)
  {
    #pragma unroll
    for (int kc = 0; kc < 2; ++kc){
      const float* p = W_ih + (size_t)RW * 16384 + kc * 32 + g * 8;
      f16x8 ahi, alo;
      cvt8(*(const float4*)p, *(const float4*)(p + 4), ahi, alo);
      size_t off = (size_t)b_own * 16384 + kc * 32 + g * 8;
      f16x8 bhi = __builtin_bit_cast(f16x8, *(const short8*)(xhi + off));
      f16x8 blo = __builtin_bit_cast(f16x8, *(const short8*)(xlo + off));
      axc0 = __builtin_amdgcn_mfma_f32_16x16x32_f16(ahi, bhi, axc0, 0,0,0);
      axc1 = __builtin_amdgcn_mfma_f32_16x16x32_f16(ahi, blo, axc1, 0,0,0);
      axc2 = __builtin_amdgcn_mfma_f32_16x16x32_f16(alo, bhi, axc2, 0,0,0);
    }
  }

  const int bbase = b_own << 6;        // 16B-unit base of B-frag row
  const int bb    = b_own & 7;

  for (int t = 0; t < 256; ++t){
    const unsigned* hb = hsteps + (size_t)t * 16384;
    uint4 d[16];

    // ---- poll h(t): bulk issue ONCE, then selective re-issue of failed chunks ----
    // chunk c (0..15): 16B at hb + (tid + (c>>1)*256)*8 + (c&1)*4
    #pragma unroll
    for (int c = 0; c < 16; ++c){
      const unsigned* p = hb + (size_t)(tid + (c >> 1) * 256) * 8 + (c & 1) * 4;
      asm volatile("global_load_dwordx4 %0, %1, off sc0 sc1" : "=v"(d[c]) : "v"(p));
    }
    asm volatile("s_waitcnt vmcnt(0)" ::: "memory");
    __builtin_amdgcn_sched_barrier(0);
    while (true){
      unsigned bad = 0u;
      #pragma unroll
      for (int c = 0; c < 16; ++c){
        unsigned a  = d[c].x > d[c].y ? d[c].x : d[c].y;
        unsigned b2 = d[c].z > d[c].w ? d[c].z : d[c].w;
        unsigned mx = a > b2 ? a : b2;
        bad |= (mx == 0xFFFFFFFFu) ? (1u << c) : 0u;
      }
      if (__all((int)(bad == 0u))) break;
      #pragma unroll
      for (int c = 0; c < 16; ++c){
        if (bad & (1u << c)){
          const unsigned* p = hb + (size_t)(tid + (c >> 1) * 256) * 8 + (c & 1) * 4;
          asm volatile("global_load_dwordx4 %0, %1, off sc0 sc1" : "=v"(d[c]) : "v"(p));
        }
      }
      asm volatile("s_waitcnt vmcnt(0)" ::: "memory");
      __builtin_amdgcn_sched_barrier(0);
    }

    // ---- prefetch W_ih(t+1) + x(t+1) fragments (cached loads, hide under unpack) ----
    float4 w0, w1, w2, w3;
    short8 xh0, xh1, xl0, xl1;
    if (t < 255){
      const float* p = W_ih + (size_t)RW * 16384 + (size_t)(t+1) * 64 + g * 8;
      w0 = *(const float4*)p;        w1 = *(const float4*)(p + 4);
      w2 = *(const float4*)(p + 32); w3 = *(const float4*)(p + 36);
      size_t off = ((size_t)b_own * 256 + (size_t)(t+1)) * 64 + g * 8;
      xh0 = *(const short8*)(xhi + off);      xh1 = *(const short8*)(xhi + off + 32);
      xl0 = *(const short8*)(xlo + off);      xl1 = *(const short8*)(xlo + off + 32);
    }

    // ---- unpack hi-plane only (v_perm) + swizzled LDS write, buffer t&1 ----
    {
      unsigned short* dstH = &hs_hi[t & 1][0];
      #pragma unroll
      for (int k = 0; k < 8; ++k){
        int U = tid + k * 256;
        int b = U >> 6, u = U & 63;
        int us = u ^ (b & 7);
        uint4 d0 = d[2*k], d1 = d[2*k+1];
        uint4 hi4;
        hi4.x = __builtin_amdgcn_perm(d0.y, d0.x, 0x07060302u);
        hi4.y = __builtin_amdgcn_perm(d0.w, d0.z, 0x07060302u);
        hi4.z = __builtin_amdgcn_perm(d1.y, d1.x, 0x07060302u);
        hi4.w = __builtin_amdgcn_perm(d1.w, d1.z, 0x07060302u);
        *(uint4*)(dstH + (size_t)((b << 6) + us) * 8) = hi4;
      }
    }
    __syncthreads();   // the ONLY barrier per step

    // ---- h @ W_hh^T via MFMA, 2-term split (whh_hi + whh_lo, h hi-plane only) ----
    f32x4 acc0 = {0.f,0.f,0.f,0.f}, acc2 = acc0;
    {
      const unsigned short* srcH = &hs_hi[t & 1][0];
      #pragma unroll
      for (int kc = 0; kc < 16; ++kc){
        int us = ((kc << 2) + g) ^ bb;
        f16x8 bhi = __builtin_bit_cast(f16x8, *(const short8*)(srcH + ((bbase + us) << 3)));
        acc0 = __builtin_amdgcn_mfma_f32_16x16x32_f16(whh_hi[kc], bhi, acc0, 0,0,0);
        acc2 = __builtin_amdgcn_mfma_f32_16x16x32_f16(whh_lo[kc], bhi, acc2, 0,0,0);
      }
    }

    // ---- gates in-thread (acc regs q=0..3 = i,f,g,o of (b_own, j_own)) ----
    f32x4 pre = acc0 + acc2 + axc0 + axc1 + axc2;
    float ig = fsig(pre[0] + bias_i);
    float fg = fsig(pre[1] + bias_f);
    float gg = ftanh(pre[2] + bias_g);
    float og = fsig(pre[3] + bias_o);
    c_state = fg * c_state + ig * gg;
    float hval = og * ftanh(c_state);

    if (t < 255){
      unsigned short hh, ll; split_f16(hval, hh, ll);
      unsigned packed = ((unsigned)hh << 16) | (unsigned)ll;   // finite => hi16 != 0xFFFF
      asm volatile("global_store_dword %0, %1, off sc0 sc1"
                   :: "v"(hsteps + (size_t)(t+1)*16384 + (size_t)b_own*512 + j_own), "v"(packed) : "memory");
    }
    out[(size_t)(b_own * 256 + t) * 512 + j_own] = fmaxf(hval, 0.f);

    // ---- x-part(t+1) from prefetched regs (pure VALU+MFMA, fills visibility gap) ----
    if (t < 255){
      f16x8 ahi0, alo0, ahi1, alo1;
      cvt8(w0, w1, ahi0, alo0);
      cvt8(w2, w3, ahi1, alo1);
      f16x8 bh0 = __builtin_bit_cast(f16x8, xh0), bl0 = __builtin_bit_cast(f16x8, xl0);
      f16x8 bh1 = __builtin_bit_cast(f16x8, xh1), bl1 = __builtin_bit_cast(f16x8, xl1);
      axc0 = __builtin_amdgcn_mfma_f32_16x16x32_f16(ahi0, bh0, axc0, 0,0,0);
      axc1 = __builtin_amdgcn_mfma_f32_16x16x32_f16(ahi0, bl0, axc1, 0,0,0);
      axc2 = __builtin_amdgcn_mfma_f32_16x16x32_f16(alo0, bh0, axc2, 0,0,0);
      axc0 = __builtin_amdgcn_mfma_f32_16x16x32_f16(ahi1, bh1, axc0, 0,0,0);
      axc1 = __builtin_amdgcn_mfma_f32_16x16x32_f16(ahi1, bl1, axc1, 0,0,0);
      axc2 = __builtin_amdgcn_mfma_f32_16x16x32_f16(alo1, bh1, axc2, 0,0,0);
    }
  }
}

// ---------------------------------------------------------------------------
extern "C" void kernel_launch(void* const* d_in, const int* in_sizes, int n_in,
                              void* d_out, int out_size, void* d_ws, size_t ws_size,
                              hipStream_t stream) {
  const float* x       = (const float*)d_in[0];
  const float* hidden0 = (const float*)d_in[1];
  const float* W_hid   = (const float*)d_in[2];
  const float* b_hid   = (const float*)d_in[3];
  const float* W_ih    = (const float*)d_in[4];
  const float* W_hh    = (const float*)d_in[5];
  const float* b_ih    = (const float*)d_in[6];
  const float* b_hh    = (const float*)d_in[7];

  float* out    = (float*)d_out;
  float* out_h0 = out + (size_t)32 * 256 * 512;

  char* ws = (char*)d_ws;
  unsigned*       flags  = (unsigned*)ws;                          // 256 B
  unsigned short* xhi    = (unsigned short*)(ws + 4096);           // 1 MB
  unsigned short* xlo    = (unsigned short*)(ws + 4096 + (1<<20)); // 1 MB
  unsigned*       hsteps = (unsigned*)(ws + 4096 + (2<<20));       // 16 MB: [256][32][512] dwords

  (void)hipMemsetAsync(flags, 0, 4096, stream);
  (void)hipMemsetAsync(hsteps, 0xFF, (size_t)256 * 16384 * 4, stream);  // sentinel

  lstm_persist<<<NBLK, 256, 0, stream>>>(
      x, hidden0, W_hid, b_hid, W_ih, W_hh, b_ih, b_hh,
      out, out_h0, flags, hsteps, xhi, xlo);
}

// Round 11
// 980.723 us; speedup vs baseline: 1.1526x; 1.1526x over previous
//
#include <hip/hip_runtime.h>
#include <math.h>

#define NBLK 32

typedef __attribute__((ext_vector_type(8))) short short8;
typedef __attribute__((ext_vector_type(8))) _Float16 f16x8;
typedef __attribute__((ext_vector_type(4))) float f32x4;

__device__ __forceinline__ void split_f16(float f, unsigned short& h, unsigned short& l){
  _Float16 hh = (_Float16)f;
  _Float16 ll = (_Float16)(f - (float)hh);
  h = __builtin_bit_cast(unsigned short, hh);
  l = __builtin_bit_cast(unsigned short, ll);
}

__device__ __forceinline__ float fsig(float xv){ return 1.f / (1.f + __expf(-xv)); }
__device__ __forceinline__ float ftanh(float xv){ return 1.f - 2.f / (1.f + __expf(2.f * xv)); }

__global__ __launch_bounds__(512, 1) void lstm_persist(
    const float* __restrict__ x,
    const float* __restrict__ hidden0,
    const float* __restrict__ W_hid,
    const float* __restrict__ b_hid,
    const float* __restrict__ W_ih,
    const float* __restrict__ W_hh,
    const float* __restrict__ b_ih,
    const float* __restrict__ b_hh,
    float* __restrict__ out,
    float* __restrict__ out_h0,
    unsigned* __restrict__ flags,           // [32] one-time x-init barrier
    unsigned short* __restrict__ hsteps,    // [256][32][512] f16-hi bits; 0xFFFF = not ready
    unsigned short* __restrict__ xhi,       // [32][256][64] f16 bits
    unsigned short* __restrict__ xlo)
{
  __shared__ unsigned short hs_hi[2][16384];  // 2 x 32KB, [32 rows][64 units of 8], XOR-swizzled

  const int tid  = threadIdx.x;               // 0..511
  const int bid  = blockIdx.x;                // 0..31
  const int lane = tid & 63;
  const int wid  = tid >> 6;   // 0..7
  const int cc   = wid & 1;    // batch half
  const int jh   = wid >> 1;   // j-quarter (4 cols each) 0..3
  const int m    = lane & 15;
  const int g    = lane >> 4;
  const int J0   = bid * 16;   // block owns hidden cols J0..J0+15
  const int gid  = bid * 512 + tid;           // 0..16383

  const int b_own = cc * 16 + m;        // C col (batch); also B-frag batch row
  const int j_own = J0 + jh * 4 + g;    // C rows g*4+q = gates q of this j
  const int RW = (m & 3) * 512 + J0 + jh * 4 + (m >> 2);   // A-row rr=jj*4+gate -> W row

  // ---------------- init: h0 = hidden0 @ W_hid^T + b_hid ----------------
  {
    int b = gid >> 9, hc = gid & 511;
    const float* hv = hidden0 + b * 64;
    const float* wv = W_hid + hc * 64;
    float acc = b_hid[hc];
    #pragma unroll
    for (int d = 0; d < 64; d += 4){
      float4 a = *(const float4*)(hv + d);
      float4 w = *(const float4*)(wv + d);
      acc += a.x*w.x + a.y*w.y + a.z*w.z + a.w*w.w;
    }
    out_h0[gid] = acc;                       // second output
    unsigned short hh, ll; split_f16(acc, hh, ll);
    unsigned vh = hh;                        // finite => never 0xFFFF
    asm volatile("global_store_short %0, %1, off sc0 sc1" :: "v"(hsteps + gid), "v"(vh) : "memory");
  }
  // ---------------- init: x -> f16 hi/lo (write-through) ----------------
  {
    const float4* x4 = (const float4*)x;
    #pragma unroll
    for (int k = 0; k < 8; ++k){
      int v = gid + k * 16384;
      float4 f = x4[v];
      unsigned short ha,la,hb2,lb2,hc2,lc2,hd,ld;
      split_f16(f.x,ha,la); split_f16(f.y,hb2,lb2);
      split_f16(f.z,hc2,lc2); split_f16(f.w,hd,ld);
      uint2 ph, pl;
      ph.x = (unsigned)ha | ((unsigned)hb2 << 16);
      ph.y = (unsigned)hc2 | ((unsigned)hd << 16);
      pl.x = (unsigned)la | ((unsigned)lb2 << 16);
      pl.y = (unsigned)lc2 | ((unsigned)ld << 16);
      asm volatile("global_store_dwordx2 %0, %1, off sc0 sc1" :: "v"(xhi + (size_t)v*4), "v"(ph) : "memory");
      asm volatile("global_store_dwordx2 %0, %1, off sc0 sc1" :: "v"(xlo + (size_t)v*4), "v"(pl) : "memory");
    }
  }
  // ---------------- own c0, exact f32 ----------------
  float c_state;
  {
    const float* hv = hidden0 + b_own * 64;
    const float* wv = W_hid + j_own * 64;
    float acc = b_hid[j_own];
    #pragma unroll
    for (int d = 0; d < 64; d += 4){
      float4 a = *(const float4*)(hv + d);
      float4 w = *(const float4*)(wv + d);
      acc += a.x*w.x + a.y*w.y + a.z*w.z + a.w*w.w;
    }
    c_state = acc;
  }

  // ---------------- W_hh fragments -> registers (once) ----------------
  f16x8 whh_hi[16], whh_lo[16];
  #pragma unroll
  for (int kc = 0; kc < 16; ++kc){
    const float* p = W_hh + RW * 512 + kc * 32 + g * 8;
    float4 f0 = *(const float4*)p;
    float4 f1 = *(const float4*)(p + 4);
    float fs[8] = {f0.x,f0.y,f0.z,f0.w,f1.x,f1.y,f1.z,f1.w};
    short8 hb8, lb8;
    #pragma unroll
    for (int i = 0; i < 8; ++i){
      unsigned short hh, ll; split_f16(fs[i], hh, ll);
      hb8[i] = (short)hh; lb8[i] = (short)ll;
    }
    whh_hi[kc] = __builtin_bit_cast(f16x8, hb8);
    whh_lo[kc] = __builtin_bit_cast(f16x8, lb8);
  }

  const float bias_i = b_ih[j_own]        + b_hh[j_own];
  const float bias_f = b_ih[512 + j_own]  + b_hh[512 + j_own];
  const float bias_g = b_ih[1024 + j_own] + b_hh[1024 + j_own];
  const float bias_o = b_ih[1536 + j_own] + b_hh[1536 + j_own];

  // ---------------- one-time barrier: x f16 conversion complete ----------------
  asm volatile("s_waitcnt vmcnt(0)" ::: "memory");
  __syncthreads();
  if (tid == 0){
    unsigned one = 1;
    asm volatile("global_store_dword %0, %1, off sc0 sc1" :: "v"(flags + bid), "v"(one) : "memory");
  }
  {
    const unsigned* fp = flags + (lane & 31);
    while (true){
      unsigned fv;
      asm volatile("global_load_dword %0, %1, off sc0 sc1\n\ts_waitcnt vmcnt(0)"
                   : "=v"(fv) : "v"(fp) : "memory");
      if (__all((int)(fv >= 1u))) break;
      __builtin_amdgcn_s_sleep(1);
    }
  }

  // persistent x@W_ih prefix-sum accumulators (x-side keeps full 3-term split)
  f32x4 axc0 = {0.f,0.f,0.f,0.f}, axc1 = axc0, axc2 = axc0;

  auto cvt8 = [](float4 f0, float4 f1, f16x8& hi, f16x8& lo){
    float fs[8] = {f0.x,f0.y,f0.z,f0.w,f1.x,f1.y,f1.z,f1.w};
    short8 hb8, lb8;
    #pragma unroll
    for (int i = 0; i < 8; ++i){
      unsigned short hh, ll; split_f16(fs[i], hh, ll);
      hb8[i] = (short)hh; lb8[i] = (short)ll;
    }
    hi = __builtin_bit_cast(f16x8, hb8);
    lo = __builtin_bit_cast(f16x8, lb8);
  };

  // step-0 x-part (cold, serial once)
  {
    #pragma unroll
    for (int kc = 0; kc < 2; ++kc){
      const float* p = W_ih + (size_t)RW * 16384 + kc * 32 + g * 8;
      f16x8 ahi, alo;
      cvt8(*(const float4*)p, *(const float4*)(p + 4), ahi, alo);
      size_t off = (size_t)b_own * 16384 + kc * 32 + g * 8;
      f16x8 bhi = __builtin_bit_cast(f16x8, *(const short8*)(xhi + off));
      f16x8 blo = __builtin_bit_cast(f16x8, *(const short8*)(xlo + off));
      axc0 = __builtin_amdgcn_mfma_f32_16x16x32_f16(ahi, bhi, axc0, 0,0,0);
      axc1 = __builtin_amdgcn_mfma_f32_16x16x32_f16(ahi, blo, axc1, 0,0,0);
      axc2 = __builtin_amdgcn_mfma_f32_16x16x32_f16(alo, bhi, axc2, 0,0,0);
    }
  }

  const int bbase = b_own << 6;        // 16B-unit base of B-frag row
  const int bb    = b_own & 7;

  for (int t = 0; t < 256; ++t){
    const unsigned short* hb = hsteps + (size_t)t * 16384;
    uint4 d[4];

    // ---- poll h(t): 32KB tile, 4 dwordx4/thread, bulk issue + sleep backoff ----
    // chunk c: 16B (8 ushorts) at unit U = tid + c*512
    while (true){
      #pragma unroll
      for (int c = 0; c < 4; ++c){
        const unsigned* p = (const unsigned*)hb + (size_t)(tid + c * 512) * 4;
        asm volatile("global_load_dwordx4 %0, %1, off sc0 sc1" : "=v"(d[c]) : "v"(p));
      }
      asm volatile("s_waitcnt vmcnt(0)" ::: "memory");
      __builtin_amdgcn_sched_barrier(0);
      int bad = 0;
      #pragma unroll
      for (int c = 0; c < 4; ++c){
        #pragma unroll
        for (int q = 0; q < 4; ++q){
          unsigned w = (q==0)?d[c].x:(q==1)?d[c].y:(q==2)?d[c].z:d[c].w;
          bad |= ((w & 0xFFFFu) == 0xFFFFu) | (w >= 0xFFFF0000u);
        }
      }
      if (!__any(bad)) break;
      __builtin_amdgcn_s_sleep(1);
    }

    // ---- prefetch W_ih(t+1) + x(t+1) fragments (cached loads, hide under stage) ----
    float4 w0, w1, w2, w3;
    short8 xh0, xh1, xl0, xl1;
    if (t < 255){
      const float* p = W_ih + (size_t)RW * 16384 + (size_t)(t+1) * 64 + g * 8;
      w0 = *(const float4*)p;        w1 = *(const float4*)(p + 4);
      w2 = *(const float4*)(p + 32); w3 = *(const float4*)(p + 36);
      size_t off = ((size_t)b_own * 256 + (size_t)(t+1)) * 64 + g * 8;
      xh0 = *(const short8*)(xhi + off);      xh1 = *(const short8*)(xhi + off + 32);
      xl0 = *(const short8*)(xlo + off);      xl1 = *(const short8*)(xlo + off + 32);
    }

    // ---- stage tile -> swizzled LDS (no unpack needed: already hi-plane) ----
    {
      unsigned short* dstH = &hs_hi[t & 1][0];
      #pragma unroll
      for (int c = 0; c < 4; ++c){
        int U = tid + c * 512;             // 0..2047
        int b = U >> 6, u = U & 63;
        int us = u ^ (b & 7);
        *(uint4*)(dstH + (size_t)((b << 6) + us) * 8) = d[c];
      }
    }
    __syncthreads();   // the ONLY barrier per step

    // ---- h @ W_hh^T via MFMA, 2-term split (W hi+lo, h hi-plane) ----
    f32x4 acc0 = {0.f,0.f,0.f,0.f}, acc2 = acc0;
    {
      const unsigned short* srcH = &hs_hi[t & 1][0];
      #pragma unroll
      for (int kc = 0; kc < 16; ++kc){
        int us = ((kc << 2) + g) ^ bb;
        f16x8 bhi = __builtin_bit_cast(f16x8, *(const short8*)(srcH + ((bbase + us) << 3)));
        acc0 = __builtin_amdgcn_mfma_f32_16x16x32_f16(whh_hi[kc], bhi, acc0, 0,0,0);
        acc2 = __builtin_amdgcn_mfma_f32_16x16x32_f16(whh_lo[kc], bhi, acc2, 0,0,0);
      }
    }

    // ---- gates in-thread (acc regs q=0..3 = i,f,g,o of (b_own, j_own)) ----
    f32x4 pre = acc0 + acc2 + axc0 + axc1 + axc2;
    float ig = fsig(pre[0] + bias_i);
    float fg = fsig(pre[1] + bias_f);
    float gg = ftanh(pre[2] + bias_g);
    float og = fsig(pre[3] + bias_o);
    c_state = fg * c_state + ig * gg;
    float hval = og * ftanh(c_state);

    if (t < 255){
      unsigned short hh, ll; split_f16(hval, hh, ll);
      unsigned vh = hh;                                       // finite => never 0xFFFF
      asm volatile("global_store_short %0, %1, off sc0 sc1"
                   :: "v"(hsteps + (size_t)(t+1)*16384 + (size_t)b_own*512 + j_own), "v"(vh) : "memory");
    }
    out[(size_t)(b_own * 256 + t) * 512 + j_own] = fmaxf(hval, 0.f);

    // ---- x-part(t+1) from prefetched regs (pure VALU+MFMA, fills visibility gap) ----
    if (t < 255){
      f16x8 ahi0, alo0, ahi1, alo1;
      cvt8(w0, w1, ahi0, alo0);
      cvt8(w2, w3, ahi1, alo1);
      f16x8 bh0 = __builtin_bit_cast(f16x8, xh0), bl0 = __builtin_bit_cast(f16x8, xl0);
      f16x8 bh1 = __builtin_bit_cast(f16x8, xh1), bl1 = __builtin_bit_cast(f16x8, xl1);
      axc0 = __builtin_amdgcn_mfma_f32_16x16x32_f16(ahi0, bh0, axc0, 0,0,0);
      axc1 = __builtin_amdgcn_mfma_f32_16x16x32_f16(ahi0, bl0, axc1, 0,0,0);
      axc2 = __builtin_amdgcn_mfma_f32_16x16x32_f16(alo0, bh0, axc2, 0,0,0);
      axc0 = __builtin_amdgcn_mfma_f32_16x16x32_f16(ahi1, bh1, axc0, 0,0,0);
      axc1 = __builtin_amdgcn_mfma_f32_16x16x32_f16(ahi1, bl1, axc1, 0,0,0);
      axc2 = __builtin_amdgcn_mfma_f32_16x16x32_f16(alo1, bh1, axc2, 0,0,0);
    }
  }
}

// ---------------------------------------------------------------------------
extern "C" void kernel_launch(void* const* d_in, const int* in_sizes, int n_in,
                              void* d_out, int out_size, void* d_ws, size_t ws_size,
                              hipStream_t stream) {
  const float* x       = (const float*)d_in[0];
  const float* hidden0 = (const float*)d_in[1];
  const float* W_hid   = (const float*)d_in[2];
  const float* b_hid   = (const float*)d_in[3];
  const float* W_ih    = (const float*)d_in[4];
  const float* W_hh    = (const float*)d_in[5];
  const float* b_ih    = (const float*)d_in[6];
  const float* b_hh    = (const float*)d_in[7];

  float* out    = (float*)d_out;
  float* out_h0 = out + (size_t)32 * 256 * 512;

  char* ws = (char*)d_ws;
  unsigned*       flags  = (unsigned*)ws;                          // 128 B
  unsigned short* xhi    = (unsigned short*)(ws + 4096);           // 1 MB
  unsigned short* xlo    = (unsigned short*)(ws + 4096 + (1<<20)); // 1 MB
  unsigned short* hsteps = (unsigned short*)(ws + 4096 + (2<<20)); // 8 MB: [256][32][512] ushorts

  (void)hipMemsetAsync(flags, 0, 4096, stream);
  (void)hipMemsetAsync(hsteps, 0xFF, (size_t)256 * 16384 * 2, stream);  // sentinel

  lstm_persist<<<NBLK, 512, 0, stream>>>(
      x, hidden0, W_hid, b_hid, W_ih, W_hh, b_ih, b_hh,
      out, out_h0, flags, hsteps, xhi, xlo);
}

// Round 14
// 571.207 us; speedup vs baseline: 1.9789x; 1.7169x over previous
//
#include <hip/hip_runtime.h>
#include <math.h>

typedef __attribute__((ext_vector_type(8))) short short8;
typedef __attribute__((ext_vector_type(8))) _Float16 f16x8;
typedef __attribute__((ext_vector_type(4))) float f32x4;
typedef __attribute__((ext_vector_type(4))) unsigned uint32x4;

__device__ __forceinline__ void split_f16(float f, unsigned short& h, unsigned short& l){
  _Float16 hh = (_Float16)f;
  _Float16 ll = (_Float16)(f - (float)hh);
  h = __builtin_bit_cast(unsigned short, hh);
  l = __builtin_bit_cast(unsigned short, ll);
}

__device__ __forceinline__ float fsig(float xv){ return 1.f / (1.f + __expf(-xv)); }
__device__ __forceinline__ float ftanh(float xv){ return 1.f - 2.f / (1.f + __expf(2.f * xv)); }

// 256 blocks, 1/CU. grp = bid&7 (XCD hint), slot = bid>>3.
// Group owns batches grp*4..grp*4+3, slot owns j = slot*16..slot*16+15.
// h exchange: producers DUAL-write (plain -> local L2, sc0sc1 -> device);
// consumers poll local with sc0 (fast path), sticky-fallback to device copy.
// Liveness never depends on block->XCD placement (G16-safe).
__global__ __launch_bounds__(256, 1) void lstm_grp(
    const float* __restrict__ x,
    const float* __restrict__ hidden0,
    const float* __restrict__ W_hid,
    const float* __restrict__ b_hid,
    const float* __restrict__ W_ih,
    const float* __restrict__ W_hh,
    const float* __restrict__ b_ih,
    const float* __restrict__ b_hh,
    float* __restrict__ out,
    float* __restrict__ out_h0,
    unsigned* __restrict__ flags,        // [256] one-time init barrier
    unsigned short* __restrict__ hloc,   // [8][256][2048] f16-hi, plain stores
    unsigned short* __restrict__ hglb,   // [8][256][2048] f16-hi, sc0sc1 stores
    unsigned short* __restrict__ xhi,    // [32][256][64] f16 bits
    unsigned short* __restrict__ xlo)
{
  __shared__ unsigned short hsb[2][16 * 64 * 8];   // 2 x 16KB; rows 4..15 unused garbage

  const int tid  = threadIdx.x;
  const int bid  = blockIdx.x;
  const int grp  = bid & 7;
  const int slot = bid >> 3;
  const int lane = tid & 63;
  const int wid  = tid >> 6;               // 0..3
  const int m    = lane & 15;
  const int g    = lane >> 4;              // 0..3
  const int J0   = slot * 16;
  const int gid  = bid * 256 + tid;        // 0..65535

  const int lbm   = m & 3;                 // local batch (B-frag col clamped)
  const int b_o   = grp * 4 + lbm;
  const int j_own = J0 + wid * 4 + g;
  const int R     = (m & 3) * 512 + J0 + wid * 4 + (m >> 2);
  const bool owner = (m < 4);

  unsigned short* hlg = hloc + (size_t)grp * 256 * 2048;
  unsigned short* hgg = hglb + (size_t)grp * 256 * 2048;

  // ---------------- init: x -> f16 hi/lo (2 float4 per thread, sc0sc1) ----------------
  {
    const float4* x4 = (const float4*)x;
    float4 f0 = x4[(size_t)gid * 2];
    float4 f1 = x4[(size_t)gid * 2 + 1];
    float fs[8] = {f0.x,f0.y,f0.z,f0.w,f1.x,f1.y,f1.z,f1.w};
    uint32x4 hv4, lv4;
    #pragma unroll
    for (int i = 0; i < 4; ++i){
      unsigned short h0b, l0b, h1b, l1b;
      split_f16(fs[2*i],   h0b, l0b);
      split_f16(fs[2*i+1], h1b, l1b);
      hv4[i] = (unsigned)h0b | ((unsigned)h1b << 16);
      lv4[i] = (unsigned)l0b | ((unsigned)l1b << 16);
    }
    asm volatile("global_store_dwordx4 %0, %1, off sc0 sc1" :: "v"(xhi + (size_t)gid*8), "v"(hv4) : "memory");
    asm volatile("global_store_dwordx4 %0, %1, off sc0 sc1" :: "v"(xlo + (size_t)gid*8), "v"(lv4) : "memory");
  }

  // ---------------- own c0/h0: exact f32 dot ----------------
  float c_state;
  {
    const float* hv = hidden0 + b_o * 64;
    const float* wv = W_hid + j_own * 64;
    float acc = b_hid[j_own];
    #pragma unroll
    for (int d = 0; d < 64; d += 4){
      float4 a = *(const float4*)(hv + d);
      float4 w = *(const float4*)(wv + d);
      acc += a.x*w.x + a.y*w.y + a.z*w.z + a.w*w.w;
    }
    c_state = acc;
    if (owner){
      out_h0[(size_t)b_o * 512 + j_own] = acc;
      unsigned short hh, ll; split_f16(acc, hh, ll);
      unsigned vh = hh;                    // finite => never 0xFFFF
      size_t off = (size_t)lbm * 512 + j_own;
      asm volatile("global_store_short %0, %1, off"         :: "v"(hlg + off), "v"(vh) : "memory");
      asm volatile("global_store_short %0, %1, off sc0 sc1" :: "v"(hgg + off), "v"(vh) : "memory");
    }
  }

  // ---------------- W_hh fragments -> registers (once) ----------------
  f16x8 whh_hi[16], whh_lo[16];
  #pragma unroll
  for (int kc = 0; kc < 16; ++kc){
    const float* p = W_hh + (size_t)R * 512 + kc * 32 + g * 8;
    float4 f0 = *(const float4*)p;
    float4 f1 = *(const float4*)(p + 4);
    float fs[8] = {f0.x,f0.y,f0.z,f0.w,f1.x,f1.y,f1.z,f1.w};
    short8 hb8, lb8;
    #pragma unroll
    for (int i = 0; i < 8; ++i){
      unsigned short hh, ll; split_f16(fs[i], hh, ll);
      hb8[i] = (short)hh; lb8[i] = (short)ll;
    }
    whh_hi[kc] = __builtin_bit_cast(f16x8, hb8);
    whh_lo[kc] = __builtin_bit_cast(f16x8, lb8);
  }

  const float bias_i = b_ih[j_own]        + b_hh[j_own];
  const float bias_f = b_ih[512 + j_own]  + b_hh[512 + j_own];
  const float bias_g = b_ih[1024 + j_own] + b_hh[1024 + j_own];
  const float bias_o = b_ih[1536 + j_own] + b_hh[1536 + j_own];

  // ---------------- one-time barrier: init stores drained & visible ----------------
  asm volatile("s_waitcnt vmcnt(0)" ::: "memory");
  __syncthreads();
  if (tid == 0){
    unsigned one = 1;
    asm volatile("global_store_dword %0, %1, off sc0 sc1" :: "v"(flags + bid), "v"(one) : "memory");
  }
  {
    const unsigned* fp = flags + lane * 4;
    while (true){
      uint32x4 fv;
      asm volatile("global_load_dwordx4 %0, %1, off sc0 sc1\n\ts_waitcnt vmcnt(0)"
                   : "=v"(fv) : "v"(fp) : "memory");
      unsigned mn0 = fv[0] < fv[1] ? fv[0] : fv[1];
      unsigned mn1 = fv[2] < fv[3] ? fv[2] : fv[3];
      unsigned mn  = mn0 < mn1 ? mn0 : mn1;
      if (__all((int)(mn >= 1u))) break;
      __builtin_amdgcn_s_sleep(1);
    }
  }

  // persistent x@W_ih prefix-sum accumulators (3-term split)
  f32x4 axc0 = {0.f,0.f,0.f,0.f}, axc1 = axc0, axc2 = axc0;

  auto cvt8 = [](float4 f0, float4 f1, f16x8& hi, f16x8& lo){
    float fs[8] = {f0.x,f0.y,f0.z,f0.w,f1.x,f1.y,f1.z,f1.w};
    short8 hb8, lb8;
    #pragma unroll
    for (int i = 0; i < 8; ++i){
      unsigned short hh, ll; split_f16(fs[i], hh, ll);
      hb8[i] = (short)hh; lb8[i] = (short)ll;
    }
    hi = __builtin_bit_cast(f16x8, hb8);
    lo = __builtin_bit_cast(f16x8, lb8);
  };

  // step-0 x-part (cold, once)
  {
    #pragma unroll
    for (int kc = 0; kc < 2; ++kc){
      const float* p = W_ih + (size_t)R * 16384 + kc * 32 + g * 8;
      f16x8 ahi, alo;
      cvt8(*(const float4*)p, *(const float4*)(p + 4), ahi, alo);
      size_t off = (size_t)b_o * 16384 + kc * 32 + g * 8;
      f16x8 bhi = __builtin_bit_cast(f16x8, *(const short8*)(xhi + off));
      f16x8 blo = __builtin_bit_cast(f16x8, *(const short8*)(xlo + off));
      axc0 = __builtin_amdgcn_mfma_f32_16x16x32_f16(ahi, bhi, axc0, 0,0,0);
      axc1 = __builtin_amdgcn_mfma_f32_16x16x32_f16(ahi, blo, axc1, 0,0,0);
      axc2 = __builtin_amdgcn_mfma_f32_16x16x32_f16(alo, bhi, axc2, 0,0,0);
    }
  }

  const int lb_st = tid >> 6;          // staging row (0..3)
  const int us_st = (tid & 63) ^ (lb_st & 7);
  bool use_local = true;

  for (int t = 0; t < 256; ++t){
    uint32x4 dv;
    bool got = false;

    // ---- fast path: poll group-local copy (sc0, L2-scope), bounded ----
    if (use_local){
      const unsigned* p = (const unsigned*)(hlg + (size_t)t * 2048) + (size_t)tid * 4;
      int tries = 0;
      while (tries < 64){
        asm volatile("global_load_dwordx4 %0, %1, off sc0\n\ts_waitcnt vmcnt(0)"
                     : "=v"(dv) : "v"(p) : "memory");
        int bad = 0;
        #pragma unroll
        for (int q = 0; q < 4; ++q){
          unsigned w = dv[q];
          bad |= ((w & 0xFFFFu) == 0xFFFFu) | (w >= 0xFFFF0000u);
        }
        if (!__any(bad)){ got = true; break; }
        __builtin_amdgcn_s_sleep(1);
        ++tries;
      }
      if (!got) use_local = false;       // sticky fallback
    }
    // ---- fallback: device-scope copy (always written) ----
    if (!got){
      const unsigned* p = (const unsigned*)(hgg + (size_t)t * 2048) + (size_t)tid * 4;
      while (true){
        asm volatile("global_load_dwordx4 %0, %1, off sc0 sc1\n\ts_waitcnt vmcnt(0)"
                     : "=v"(dv) : "v"(p) : "memory");
        int bad = 0;
        #pragma unroll
        for (int q = 0; q < 4; ++q){
          unsigned w = dv[q];
          bad |= ((w & 0xFFFFu) == 0xFFFFu) | (w >= 0xFFFF0000u);
        }
        if (!__any(bad)) break;
        __builtin_amdgcn_s_sleep(1);
      }
    }

    // ---- prefetch W_ih(t+1) + x(t+1) (plain cached; consumed after gates) ----
    float4 w0, w1, w2, w3;
    short8 xh0, xh1, xl0, xl1;
    if (t < 255){
      const float* p = W_ih + (size_t)R * 16384 + (size_t)(t+1) * 64 + g * 8;
      w0 = *(const float4*)p;        w1 = *(const float4*)(p + 4);
      w2 = *(const float4*)(p + 32); w3 = *(const float4*)(p + 36);
      size_t off = ((size_t)b_o * 256 + (size_t)(t+1)) * 64 + g * 8;
      xh0 = *(const short8*)(xhi + off);      xh1 = *(const short8*)(xhi + off + 32);
      xl0 = *(const short8*)(xlo + off);      xl1 = *(const short8*)(xlo + off + 32);
    }

    // ---- stage 4KB tile -> swizzled LDS, buffer t&1 ----
    *(uint32x4*)(&hsb[t & 1][(size_t)(lb_st * 64 + us_st) * 8]) = dv;
    __syncthreads();   // the ONLY barrier per step

    // ---- h @ W_hh^T via MFMA (2-term W split, h hi-plane) ----
    f32x4 acc0 = {0.f,0.f,0.f,0.f}, acc2 = acc0;
    {
      const unsigned short* srcH = &hsb[t & 1][0];
      #pragma unroll
      for (int kc = 0; kc < 16; ++kc){
        int us = (kc * 4 + g) ^ (m & 7);
        f16x8 bhi = __builtin_bit_cast(f16x8, *(const short8*)(srcH + (size_t)(m * 64 + us) * 8));
        acc0 = __builtin_amdgcn_mfma_f32_16x16x32_f16(whh_hi[kc], bhi, acc0, 0,0,0);
        acc2 = __builtin_amdgcn_mfma_f32_16x16x32_f16(whh_lo[kc], bhi, acc2, 0,0,0);
      }
    }

    // ---- gates in-thread; owners dual-store h(t+1) ----
    f32x4 pre = acc0 + acc2 + axc0 + axc1 + axc2;
    float ig = fsig(pre[0] + bias_i);
    float fg = fsig(pre[1] + bias_f);
    float gg = ftanh(pre[2] + bias_g);
    float og = fsig(pre[3] + bias_o);
    c_state = fg * c_state + ig * gg;
    float hval = og * ftanh(c_state);

    if (owner){
      if (t < 255){
        unsigned short hh, ll; split_f16(hval, hh, ll);
        unsigned vh = hh;                              // finite => never 0xFFFF
        size_t off = (size_t)(t+1) * 2048 + (size_t)lbm * 512 + j_own;
        asm volatile("global_store_short %0, %1, off"         :: "v"(hlg + off), "v"(vh) : "memory");
        asm volatile("global_store_short %0, %1, off sc0 sc1" :: "v"(hgg + off), "v"(vh) : "memory");
      }
      out[((size_t)b_o * 256 + t) * 512 + j_own] = fmaxf(hval, 0.f);
    }

    // ---- x-part(t+1) from prefetched regs ----
    if (t < 255){
      f16x8 ahi0, alo0, ahi1, alo1;
      cvt8(w0, w1, ahi0, alo0);
      cvt8(w2, w3, ahi1, alo1);
      f16x8 bh0 = __builtin_bit_cast(f16x8, xh0), bl0 = __builtin_bit_cast(f16x8, xl0);
      f16x8 bh1 = __builtin_bit_cast(f16x8, xh1), bl1 = __builtin_bit_cast(f16x8, xl1);
      axc0 = __builtin_amdgcn_mfma_f32_16x16x32_f16(ahi0, bh0, axc0, 0,0,0);
      axc1 = __builtin_amdgcn_mfma_f32_16x16x32_f16(ahi0, bl0, axc1, 0,0,0);
      axc2 = __builtin_amdgcn_mfma_f32_16x16x32_f16(alo0, bh0, axc2, 0,0,0);
      axc0 = __builtin_amdgcn_mfma_f32_16x16x32_f16(ahi1, bh1, axc0, 0,0,0);
      axc1 = __builtin_amdgcn_mfma_f32_16x16x32_f16(ahi1, bl1, axc1, 0,0,0);
      axc2 = __builtin_amdgcn_mfma_f32_16x16x32_f16(alo1, bh1, axc2, 0,0,0);
    }
  }
}

// ---------------------------------------------------------------------------
extern "C" void kernel_launch(void* const* d_in, const int* in_sizes, int n_in,
                              void* d_out, int out_size, void* d_ws, size_t ws_size,
                              hipStream_t stream) {
  const float* x       = (const float*)d_in[0];
  const float* hidden0 = (const float*)d_in[1];
  const float* W_hid   = (const float*)d_in[2];
  const float* b_hid   = (const float*)d_in[3];
  const float* W_ih    = (const float*)d_in[4];
  const float* W_hh    = (const float*)d_in[5];
  const float* b_ih    = (const float*)d_in[6];
  const float* b_hh    = (const float*)d_in[7];

  float* out    = (float*)d_out;
  float* out_h0 = out + (size_t)32 * 256 * 512;

  char* ws = (char*)d_ws;
  unsigned*       flags = (unsigned*)ws;                            // 1 KB
  unsigned short* xhi   = (unsigned short*)(ws + 4096);             // 1 MB
  unsigned short* xlo   = (unsigned short*)(ws + 4096 + (1<<20));   // 1 MB
  unsigned short* hloc  = (unsigned short*)(ws + 4096 + (2<<20));   // 8 MB
  unsigned short* hglb  = (unsigned short*)(ws + 4096 + (2<<20) + (8<<20)); // 8 MB

  (void)hipMemsetAsync(ws, 0, 4096, stream);
  (void)hipMemsetAsync(hloc, 0xFF, (size_t)8 * 256 * 2048 * 2, stream);
  (void)hipMemsetAsync(hglb, 0xFF, (size_t)8 * 256 * 2048 * 2, stream);

  lstm_grp<<<256, 256, 0, stream>>>(
      x, hidden0, W_hid, b_hid, W_ih, W_hh, b_ih, b_hh,
      out, out_h0, flags, hloc, hglb, xhi, xlo);
}